// Round 13
// baseline (538.612 us; speedup 1.0000x reference)
//
#include <hip/hip_runtime.h>
#include <hip/hip_bf16.h>
#include <math.h>

// Problem constants
#define B_   16
#define L_   196
#define FD_  2048
#define N_   1000
#define WD_  300
#define HD_  512
#define DD_  5
#define E_   50000
#define TMAX_ 5
#define NIMG_ 1000
#define WDP_ 320   // WD_ padded to multiple of 32 (zero-filled)
#define LP_  224   // L_ padded to multiple of 32 (zero-filled)
#define EKP_ 640   // edge-MLP K: [embH_pad(320) | embH_pad(320)]

typedef __attribute__((ext_vector_type(8))) short bf16x8;
typedef __attribute__((ext_vector_type(4))) float f32x4;

// Double-buffered gl16 staging:
// mm split: 2 x (AsH 8192 + AsL 8192 + BsH 4096 + BsL 4096) = 49152
// mm ns   : 2 x (8192 + 4096) = 24576
// edge    : 2 x (As 4096 + Bs 16384) = 40960, extras at 40960..42752
#define SMEM_MEGA1    49152
#define SMEM_MM_SPLIT 49152
#define SMEM_MM_NS    24576
#define SMEM_PREP     4352

// raw barrier / counted waits (memory clobber pins memory-op ordering)
#define SBAR()    asm volatile("s_barrier" ::: "memory")
#define WVM(N)    asm volatile("s_waitcnt vmcnt(" #N ")" ::: "memory")

__device__ __forceinline__ short bf_hi(float x) {
    unsigned u = __float_as_uint(x);
    unsigned r = u + 0x7fffu + ((u >> 16) & 1u);
    return (short)(r >> 16);
}
__device__ __forceinline__ float bf2f_(short s) {
    return __uint_as_float(((unsigned)(unsigned short)s) << 16);
}

// direct global->LDS 16B copy (dest = wave-uniform base + lane*16)
__device__ __forceinline__ void gl16(const short* g, char* l) {
    __builtin_amdgcn_global_load_lds(
        (const __attribute__((address_space(1))) void*)g,
        (__attribute__((address_space(3))) void*)l, 16, 0, 0);
}

// ---------------------------------------------------------------------------
// MFMA GEMM core v5 (validated rounds 6/7/9/12): gl16 into double-buffered
// unpadded [row][32] LDS, both-sides XOR-chunk swizzle (BANK_CONFLICT=0),
// 2-deep pipeline with counted vmcnt (tile k+1 in flight across barriers).
// ---------------------------------------------------------------------------
#define OUT_SPLIT 1
#define OUT_SC    2
#define OUT_F1T   3
#define OUT_H0    4

template<int OUTMODE, bool SPLIT>
__device__ __forceinline__ void mm_core(
    char* sm, int bx, int by, int zb,
    const short* __restrict__ Ah, const short* __restrict__ Al,
    const short* __restrict__ Bh, const short* __restrict__ Bl,
    const float* __restrict__ bias, void* __restrict__ C0, void* __restrict__ C1,
    void* __restrict__ C2, const float* __restrict__ W2,
    int M, int N, int K, int kbeg, int kend)
{
    const int PBUF = SPLIT ? 24576 : 12288;
    char* AsH = sm;                               // [128][32] shorts = 8192 B
    char* AsL = sm + 8192;                        // SPLIT only
    char* BsH = sm + (SPLIT ? 16384 : 8192);      // [64][32] shorts = 4096 B
    char* BsL = sm + 20480;                       // SPLIT only
    int t = threadIdx.x;
    int lane = t & 63, w = t >> 6;
    int q = lane >> 4, r = lane & 15;
    int row0 = by * 128, col0 = bx * 64;

    int srow = t >> 2, cd = t & 3;
    int cg = cd ^ ((srow >> 1) & 3);              // pre-swizzled source chunk
    int gA0 = row0 + srow;       if (gA0 >= M) gA0 = M - 1;
    int gA1 = row0 + 64 + srow;  if (gA1 >= M) gA1 = M - 1;
    int gB  = col0 + srow;       if (gB  >= N) gB  = N - 1;
    const short* pA0 = Ah + (long)gA0 * K + cg * 8 + kbeg;
    const short* pA1 = Ah + (long)gA1 * K + cg * 8 + kbeg;
    const short* pB  = Bh + (long)gB  * K + cg * 8 + kbeg;
    const short* pA0l = Ah; const short* pA1l = Ah; const short* pBl = Bh;
    if (SPLIT) {
        pA0l = Al + (long)gA0 * K + cg * 8 + kbeg;
        pA1l = Al + (long)gA1 * K + cg * 8 + kbeg;
        pBl  = Bl + (long)gB  * K + cg * 8 + kbeg;
    }
    char* dA0 = AsH + t * 16;
    char* dA1 = AsH + 4096 + t * 16;
    char* dB  = BsH + t * 16;
    char* dA0l = AsL + t * 16;
    char* dA1l = AsL + 4096 + t * 16;
    char* dBl  = BsL + t * 16;

    int x = (q ^ ((r >> 1) & 3)) * 16;
    int aoff0 = (w * 32 + r) * 64 + x;
    int aoff1 = aoff0 + 1024;                     // +16 rows
    int boff[4];
    #pragma unroll
    for (int ct = 0; ct < 4; ct++) boff[ct] = (ct * 16 + r) * 64 + x;

    f32x4 zero4 = {0.f, 0.f, 0.f, 0.f};
    f32x4 acc[2][4];
    #pragma unroll
    for (int i = 0; i < 2; i++)
        #pragma unroll
        for (int j = 0; j < 4; j++) acc[i][j] = zero4;

    auto stage = [&](int ks) {
        int off = (ks & 1) * PBUF;
        int ko = ks * 32;
        gl16(pA0 + ko, dA0 + off);
        gl16(pA1 + ko, dA1 + off);
        gl16(pB  + ko, dB  + off);
        if (SPLIT) {
            gl16(pA0l + ko, dA0l + off);
            gl16(pA1l + ko, dA1l + off);
            gl16(pBl  + ko, dBl  + off);
        }
    };

    int nk = (kend - kbeg) >> 5;
    stage(0);
    for (int ks = 0; ks < nk; ks++) {
        if (ks + 1 < nk) {
            stage(ks + 1);                 // into buf^1 (safe: prev trailing bar)
            if (SPLIT) { WVM(6); } else { WVM(3); }   // wait tile ks only
        } else {
            WVM(0);
        }
        SBAR();                            // tile ks visible to all waves

        int cur = (ks & 1) * PBUF;
        bf16x8 ah0 = *(const bf16x8*)(AsH + cur + aoff0);
        bf16x8 ah1 = *(const bf16x8*)(AsH + cur + aoff1);
        bf16x8 al0, al1;
        if (SPLIT) {
            al0 = *(const bf16x8*)(AsL + cur + aoff0);
            al1 = *(const bf16x8*)(AsL + cur + aoff1);
        }
        #pragma unroll
        for (int ct = 0; ct < 4; ct++) {
            bf16x8 bh = *(const bf16x8*)(BsH + cur + boff[ct]);
            acc[0][ct] = __builtin_amdgcn_mfma_f32_16x16x32_bf16(ah0, bh, acc[0][ct], 0, 0, 0);
            acc[1][ct] = __builtin_amdgcn_mfma_f32_16x16x32_bf16(ah1, bh, acc[1][ct], 0, 0, 0);
            if (SPLIT) {
                acc[0][ct] = __builtin_amdgcn_mfma_f32_16x16x32_bf16(al0, bh, acc[0][ct], 0, 0, 0);
                acc[1][ct] = __builtin_amdgcn_mfma_f32_16x16x32_bf16(al1, bh, acc[1][ct], 0, 0, 0);
                bf16x8 bl = *(const bf16x8*)(BsL + cur + boff[ct]);
                acc[0][ct] = __builtin_amdgcn_mfma_f32_16x16x32_bf16(ah0, bl, acc[0][ct], 0, 0, 0);
                acc[1][ct] = __builtin_amdgcn_mfma_f32_16x16x32_bf16(ah1, bl, acc[1][ct], 0, 0, 0);
            }
        }
        if (ks + 1 < nk) SBAR();           // reads done before buf restage (ks+2)
    }

    if (OUTMODE == OUT_H0) {
        float s[2][4][DD_];
        #pragma unroll
        for (int i = 0; i < 2; i++)
            #pragma unroll
            for (int reg = 0; reg < 4; reg++)
                #pragma unroll
                for (int d = 0; d < DD_; d++) s[i][reg][d] = 0.f;
        #pragma unroll
        for (int i = 0; i < 2; i++) {
            #pragma unroll
            for (int ct = 0; ct < 4; ct++) {
                int n = col0 + ct * 16 + r;
                float w2v[DD_];
                #pragma unroll
                for (int d = 0; d < DD_; d++) w2v[d] = W2[n * DD_ + d];
                float b1 = bias[n];
                #pragma unroll
                for (int reg = 0; reg < 4; reg++) {
                    int m = row0 + w * 32 + i * 16 + q * 4 + reg;
                    if (m >= M) continue;
                    float val = fmaxf(acc[i][ct][reg] + b1, 0.f);
                    #pragma unroll
                    for (int d = 0; d < DD_; d++) s[i][reg][d] = fmaf(val, w2v[d], s[i][reg][d]);
                }
            }
        }
        #pragma unroll
        for (int i = 0; i < 2; i++)
            #pragma unroll
            for (int reg = 0; reg < 4; reg++)
                #pragma unroll
                for (int d = 0; d < DD_; d++) {
                    float v = s[i][reg][d];
                    v += __shfl_xor(v, 1);
                    v += __shfl_xor(v, 2);
                    v += __shfl_xor(v, 4);
                    v += __shfl_xor(v, 8);
                    if (r == 0) {
                        int m = row0 + w * 32 + i * 16 + q * 4 + reg;
                        if (m < M)
                            atomicAdd(&((float*)C0)[(long)m * (B_ * DD_) + zb * DD_ + d], v);
                    }
                }
        return;
    }

    #pragma unroll
    for (int i = 0; i < 2; i++) {
        #pragma unroll
        for (int ct = 0; ct < 4; ct++) {
            #pragma unroll
            for (int reg = 0; reg < 4; reg++) {
                int m = row0 + w * 32 + i * 16 + q * 4 + reg;
                int n = col0 + ct * 16 + r;
                if (m >= M || n >= N) continue;
                float v = acc[i][ct][reg];
                if (OUTMODE == OUT_SC) {
                    ((float*)C0)[(long)m * N + n] = v;
                } else if (OUTMODE == OUT_F1T) {
                    int b = m / 196, l = m - b * 196;
                    ((short*)C2)[((long)b * 512 + n) * LP_ + l] = bf_hi(v);
                } else { // OUT_SPLIT
                    float v2 = v + bias[n];
                    long idx = (long)m * N + n;
                    short hi = bf_hi(v2);
                    ((short*)C0)[idx] = hi;
                    ((short*)C1)[idx] = bf_hi(v2 - bf2f_(hi));
                }
            }
        }
    }
}

// ---------------------------------------------------------------------------
// Edge MLP core v3 (validated round 6)
// ---------------------------------------------------------------------------
__device__ __forceinline__ void edge_core(
    char* sm, int be,
    const short* __restrict__ embedH, const int* __restrict__ edges,
    const short* __restrict__ Wr1T, const float* __restrict__ br1,
    const float* __restrict__ Wr2, const float* __restrict__ br2,
    float* __restrict__ prop)
{
    const int EPBUF = 20480;
    char* As = sm;                 // [64][32] shorts  = 4096 B
    char* Bs = sm + 4096;          // [256][32] shorts = 16384 B
    int* src = (int*)(sm + 40960);
    int* dst = (int*)(sm + 41216);
    float (*part)[5] = (float(*)[5])(sm + 41472);
    int t = threadIdx.x;
    int e0 = be * 64;
    if (t < 64) {
        int e = e0 + t;
        src[t] = (e < E_) ? edges[e] : 0;
        dst[t] = (e < E_) ? edges[E_ + e] : 0;
    }
    __syncthreads();
    int lane = t & 63, w = t >> 6, q = lane >> 4, r = lane & 15;
    f32x4 zero4 = {0.f, 0.f, 0.f, 0.f};
    f32x4 acc[4][4];
    #pragma unroll
    for (int i = 0; i < 4; i++)
        #pragma unroll
        for (int j = 0; j < 4; j++) acc[i][j] = zero4;

    int srow = t >> 2, cd = t & 3;
    int cg = cd ^ ((srow >> 1) & 3);              // pre-swizzled source chunk
    const short* baseS = embedH + (long)src[srow] * WDP_ + cg * 8;
    const short* baseD = embedH + (long)dst[srow] * WDP_ + cg * 8;
    const short* pB = Wr1T + (long)srow * EKP_ + cg * 8;   // + i*64*EKP_
    char* dA = As + t * 16;
    char* dB = Bs + t * 16;                        // + i*4096

    int x = (q ^ ((r >> 1) & 3)) * 16;
    int aoff[4], boff[4];
    #pragma unroll
    for (int i = 0; i < 4; i++) {
        aoff[i] = (i * 16 + r) * 64 + x;
        boff[i] = (w * 64 + i * 16 + r) * 64 + x;
    }

    auto estage = [&](int ks) {
        int off = (ks & 1) * EPBUF;
        const short* pa = (ks < 10) ? baseS + ks * 32 : baseD + (ks - 10) * 32;
        gl16(pa, dA + off);
        #pragma unroll
        for (int i = 0; i < 4; i++)
            gl16(pB + (long)i * 64 * EKP_ + ks * 32, dB + i * 4096 + off);
    };

    estage(0);
    for (int ks = 0; ks < 20; ks++) {
        if (ks + 1 < 20) {
            estage(ks + 1);
            WVM(5);
        } else {
            WVM(0);
        }
        SBAR();

        int cur = (ks & 1) * EPBUF;
        bf16x8 af[4], bfr[4];
        #pragma unroll
        for (int rt = 0; rt < 4; rt++) af[rt] = *(const bf16x8*)(As + cur + aoff[rt]);
        #pragma unroll
        for (int ct = 0; ct < 4; ct++) bfr[ct] = *(const bf16x8*)(Bs + cur + boff[ct]);
        #pragma unroll
        for (int rt = 0; rt < 4; rt++)
            #pragma unroll
            for (int ct = 0; ct < 4; ct++)
                acc[rt][ct] = __builtin_amdgcn_mfma_f32_16x16x32_bf16(af[rt], bfr[ct], acc[rt][ct], 0, 0, 0);
        if (ks + 1 < 20) SBAR();
    }
    float b1v[4], w2v[4];
    #pragma unroll
    for (int ct = 0; ct < 4; ct++) {
        int u = w * 64 + ct * 16 + r;
        b1v[ct] = br1[u];
        w2v[ct] = Wr2[u];
    }
    #pragma unroll
    for (int rt = 0; rt < 4; rt++) {
        #pragma unroll
        for (int reg = 0; reg < 4; reg++) {
            float s = 0.f;
            #pragma unroll
            for (int ct = 0; ct < 4; ct++)
                s = fmaf(fmaxf(acc[rt][ct][reg] + b1v[ct], 0.f), w2v[ct], s);
            s += __shfl_xor(s, 1);
            s += __shfl_xor(s, 2);
            s += __shfl_xor(s, 4);
            s += __shfl_xor(s, 8);
            if (r == 0) part[rt * 16 + q * 4 + reg][w] = s;
        }
    }
    __syncthreads();
    if (t < 64 && e0 + t < E_) {
        float s = part[t][0] + part[t][1] + part[t][2] + part[t][3];
        atomicAdd(&prop[(long)src[t] * N_ + dst[t]], tanhf(s + br2[0]));
    }
}

// ---------------------------------------------------------------------------
// transpose+convert core. Kd = data K (loads), Ks = storage stride/write bound
// ---------------------------------------------------------------------------
__device__ __forceinline__ void transconv_core(
    char* sm, int bx, int by,
    const float* __restrict__ in, short* __restrict__ outH, short* __restrict__ outL,
    int Kd, int N, int Ks)
{
    float (*tile)[33] = (float(*)[33])sm;
    int k0 = bx * 32, n0 = by * 32;
    int t = threadIdx.x;
    int tr = t >> 5, tc = t & 31;
    #pragma unroll
    for (int i = 0; i < 4; i++) {
        int k = k0 + tr + i * 8, n = n0 + tc;
        tile[tr + i * 8][tc] = (k < Kd && n < N) ? in[(long)k * N + n] : 0.f;
    }
    __syncthreads();
    #pragma unroll
    for (int i = 0; i < 4; i++) {
        int n = n0 + tr + i * 8, k = k0 + tc;
        if (n < N && k < Ks) {
            float x = tile[tc][tr + i * 8];
            short hi = bf_hi(x);
            outH[(long)n * Ks + k] = hi;
            if (outL) outL[(long)n * Ks + k] = bf_hi(x - bf2f_(hi));
        }
    }
}

// ---------------------------------------------------------------------------
// K0: all prep. pooled branch float4-ized (32 blocks). F1T zeroes pad cols only.
// ---------------------------------------------------------------------------
__global__ __launch_bounds__(256) void prep(
    float* __restrict__ prop, float* __restrict__ Ht0, const float* __restrict__ bf2,
    const float* __restrict__ feats, float* __restrict__ pooled,
    short* __restrict__ featsH, short* __restrict__ featsL,
    const float* __restrict__ embed, short* __restrict__ embH, short* __restrict__ embL,
    const float* __restrict__ W_key, const float* __restrict__ Wf1,
    short* __restrict__ WkfH, short* __restrict__ WkfL,
    const float* __restrict__ W_query, short* __restrict__ WqTh, short* __restrict__ WqTl,
    const float* __restrict__ Wr1, short* __restrict__ Wr1T, short* __restrict__ F1T)
{
    __shared__ __align__(16) char sm[SMEM_PREP];
    int b = blockIdx.x, t = threadIdx.x;
    if (b < 977) {
        int i = (b * 256 + t) * 4;
        if (i < N_ * N_) { float4 z = {0.f, 0.f, 0.f, 0.f}; *(float4*)(prop + i) = z; }
    } else if (b < 1290) {
        int i = (b - 977) * 256 + t;
        if (i < N_ * B_ * DD_) Ht0[i] = bf2[i % DD_];
    } else if (b < 1322) {
        // pooled: float4 per thread (8192 threads = 32 blocks)
        int idx = (b - 1290) * 256 + t;
        int bb = idx >> 9, f4 = (idx & 511) * 4;
        const float* p = feats + (long)bb * L_ * FD_ + f4;
        float4 acc = {0.f, 0.f, 0.f, 0.f};
        for (int l = 0; l < L_; l++) {
            float4 v = *(const float4*)(p + (long)l * FD_);
            acc.x += v.x; acc.y += v.y; acc.z += v.z; acc.w += v.w;
        }
        const float inv = 1.0f / L_;
        acc.x *= inv; acc.y *= inv; acc.z *= inv; acc.w *= inv;
        *(float4*)(pooled + (long)bb * FD_ + f4) = acc;
    } else if (b < 4458) {
        long i = ((long)(b - 1322) * 256 + t) * 8;
        float4 v0 = *(const float4*)(feats + i);
        float4 v1 = *(const float4*)(feats + i + 4);
        float xs[8] = {v0.x, v0.y, v0.z, v0.w, v1.x, v1.y, v1.z, v1.w};
        short h[8], l8[8];
        #pragma unroll
        for (int j = 0; j < 8; j++) {
            h[j] = bf_hi(xs[j]);
            l8[j] = bf_hi(xs[j] - bf2f_(h[j]));
        }
        *(int4*)(featsH + i) = *(int4*)h;
        *(int4*)(featsL + i) = *(int4*)l8;
    } else if (b < 4771) {
        // embed -> embH/embL, strided WDP_=320, zero pad cols 300..319
        int i = ((b - 4458) * 256 + t) * 4;
        if (i < N_ * WDP_) {
            int n = i / WDP_, c = i - n * WDP_;
            short h[4], l4[4];
            if (c < WD_) {     // WD_%4==0, no straddle
                float4 v = *(const float4*)(embed + (long)n * WD_ + c);
                float xs[4] = {v.x, v.y, v.z, v.w};
                #pragma unroll
                for (int j = 0; j < 4; j++) {
                    h[j] = bf_hi(xs[j]);
                    l4[j] = bf_hi(xs[j] - bf2f_(h[j]));
                }
            } else {
                #pragma unroll
                for (int j = 0; j < 4; j++) { h[j] = 0; l4[j] = 0; }
            }
            *(int2*)(embH + (long)n * WDP_ + c) = *(int2*)h;
            *(int2*)(embL + (long)n * WDP_ + c) = *(int2*)l4;
        }
    } else if (b < 5795) {
        int bb = b - 4771;
        transconv_core(sm, bb % 64, bb / 64, W_key, WkfH, WkfL, FD_, HD_, FD_);
    } else if (b < 6819) {
        int bb = b - 5795;
        transconv_core(sm, bb % 64, bb / 64, Wf1, WkfH + (size_t)512 * FD_, nullptr, FD_, HD_, FD_);
    } else if (b < 6979) {
        int bb = b - 6819;
        transconv_core(sm, bb % 10, bb / 10, W_query, WqTh, WqTl, WD_, HD_, WDP_);
    } else if (b < 7139) {
        // Wr1 [600][256] -> Wr1T640 [256][640]: out col k<320 <- row k (valid k<300),
        // k>=320 <- row k-20 (valid k<620); stripes zeroed.
        int bb = b - 6979;                 // 160 blocks: 20 k-tiles x 8 n-tiles
        int bx = bb % 20, by = bb / 20;
        float (*tile)[33] = (float(*)[33])sm;
        int k0 = bx * 32, n0 = by * 32;
        int tr = t >> 5, tc = t & 31;
        #pragma unroll
        for (int i = 0; i < 4; i++) {
            int kout = k0 + tr + i * 8, n = n0 + tc;
            int kin = (kout < 320) ? kout : kout - 20;
            bool valid = (kout < 320) ? (kout < 300) : (kout < 620);
            tile[tr + i * 8][tc] = valid ? Wr1[(long)kin * 256 + n] : 0.f;
        }
        __syncthreads();
        #pragma unroll
        for (int i = 0; i < 4; i++) {
            int n = n0 + tr + i * 8, k = k0 + tc;
            Wr1T[(long)n * EKP_ + k] = bf_hi(tile[tc][tr + i * 8]);
        }
    } else {
        // zero ONLY F1T pad cols 196..223 (7 int2 per row, 8192 rows = 224 blocks)
        int idx = (b - 7139) * 256 + t;    // 57344 = 8192 rows * 7
        int row = idx / 7, j = idx - row * 7;
        int2 z2; z2.x = 0; z2.y = 0;
        *(int2*)(F1T + (long)row * LP_ + 196 + j * 4) = z2;
    }
}

// ---------------------------------------------------------------------------
// K1: FUSED keys(split) + F1 + queries + edge + clf (1750 blocks, round-7 clf:
// round-8 lesson — any branch's VGPR taxes every branch's occupancy)
// ---------------------------------------------------------------------------
__global__ __launch_bounds__(256) void mega1(
    const short* __restrict__ featsH, const short* __restrict__ featsL,
    const short* __restrict__ WkfH, const short* __restrict__ WkfL,
    const float* __restrict__ b_key, short* __restrict__ keysH, short* __restrict__ keysL,
    short* __restrict__ F1T,
    const short* __restrict__ embH, const short* __restrict__ embL,
    const short* __restrict__ WqTh, const short* __restrict__ WqTl,
    const float* __restrict__ b_query, short* __restrict__ qH, short* __restrict__ qL,
    const int* __restrict__ edges, const short* __restrict__ Wr1T,
    const float* __restrict__ br1, const float* __restrict__ Wr2,
    const float* __restrict__ br2, float* __restrict__ prop,
    const float* __restrict__ pooled, const float* __restrict__ W_clf,
    const float* __restrict__ b_clf, float* __restrict__ Pimg)
{
    __shared__ __align__(16) char sm[SMEM_MEGA1];
    int b = blockIdx.x;
    if (b < 200) {
        int l = (b & 7) * 25 + (b >> 3);          // XCD-chunked, G=200
        mm_core<OUT_SPLIT, true>(sm, l & 7, l >> 3, 0,
            featsH, featsL, WkfH, WkfL, b_key,
            keysH, keysL, nullptr, nullptr, B_ * L_, 512, FD_, 0, FD_);
    } else if (b < 400) {
        int bb = b - 200;
        int l = (bb & 7) * 25 + (bb >> 3);        // XCD-chunked, G=200
        mm_core<OUT_F1T, false>(sm, l & 7, l >> 3, 0,
            featsH, nullptr, WkfH + (size_t)512 * FD_, nullptr, nullptr,
            nullptr, nullptr, F1T, nullptr, B_ * L_, 512, FD_, 0, FD_);
    } else if (b < 464) {
        int bb = b - 400;
        int l = (bb & 7) * 8 + (bb >> 3);         // XCD-chunked, G=64
        mm_core<OUT_SPLIT, true>(sm, l & 7, l >> 3, 0,
            embH, embL, WqTh, WqTl, b_query,
            qH, qL, nullptr, nullptr, N_, HD_, WDP_, 0, WDP_);
    } else if (b < 1246) {
        edge_core(sm, b - 464, embH, edges, Wr1T, br1, Wr2, br2, prop);
    } else {
        int bb = b - 1246;
        int ks = bb / 63, ix = bb % 63;
        int i = ix * 256 + threadIdx.x;
        if (i < B_ * NIMG_) {
            int bi = i / NIMG_, n = i % NIMG_;
            const float* p = pooled + (long)bi * FD_ + ks * 256;
            const float* w = W_clf + (long)(ks * 256) * NIMG_ + n;
            float acc = (ks == 0) ? b_clf[n] : 0.f;
            #pragma unroll 4
            for (int k = 0; k < 256; k++) acc = fmaf(p[k], w[(long)k * NIMG_], acc);
            Pimg[(long)ks * (B_ * NIMG_) + i] = acc;
        }
    }
}

// ---------------------------------------------------------------------------
// K2: scores GEMM, single K=512 plane (512 blocks x 16 k-steps) + softmax_img
// ---------------------------------------------------------------------------
__global__ __launch_bounds__(256) void mega2(
    const short* __restrict__ qH, const short* __restrict__ qL,
    const short* __restrict__ keysH, const short* __restrict__ keysL,
    float* __restrict__ Pattn,
    const float* __restrict__ Pimg, float* __restrict__ out_img)
{
    __shared__ __align__(16) char sm[SMEM_MM_SPLIT];
    int b = blockIdx.x;
    if (b < 512) {
        int l = (b & 7) * 64 + (b >> 3);          // XCD-chunked, G=512
        int zb = l >> 5, by = (l >> 2) & 7, bx = l & 3;
        const short* Bh = keysH + (long)zb * L_ * HD_;
        const short* Bl = keysL + (long)zb * L_ * HD_;
        float* C0 = Pattn + (long)zb * N_ * L_;
        mm_core<OUT_SC, true>(sm, bx, by, 0, qH, qL, Bh, Bl, nullptr,
                              C0, nullptr, nullptr, nullptr,
                              N_, L_, HD_, 0, HD_);
    } else {
        int t = threadIdx.x;
        int wave = (b - 512) * 4 + (t >> 6), lane = t & 63;
        if (wave >= B_) return;
        const int PER = (NIMG_ + 63) / 64;
        float v[PER];
        float m = -1e30f;
        int cnt = 0;
        for (int k = lane; k < NIMG_; k += 64) {
            float s = 0.f;
            #pragma unroll
            for (int ks = 0; ks < 8; ks++) s += Pimg[(long)ks * (B_ * NIMG_) + wave * NIMG_ + k];
            v[cnt] = s; m = fmaxf(m, s); cnt++;
        }
        #pragma unroll
        for (int off = 32; off; off >>= 1) m = fmaxf(m, __shfl_xor(m, off));
        float s = 0.f;
        for (int i = 0; i < cnt; i++) { v[i] = expf(v[i] - m); s += v[i]; }
        #pragma unroll
        for (int off = 32; off; off >>= 1) s += __shfl_xor(s, off);
        float inv = 1.f / s;
        cnt = 0;
        for (int k = lane; k < NIMG_; k += 64) out_img[(long)wave * NIMG_ + k] = v[cnt++] * inv;
    }
}

// ---------------------------------------------------------------------------
// K3: softmax over 196 of single-plane P; writes out_attn fp32 + attnH bf16
// ---------------------------------------------------------------------------
__global__ void softmax_attn(const float* __restrict__ P0,
                             float* __restrict__ X, short* __restrict__ Xb, int rows)
{
    int gid = blockIdx.x * blockDim.x + threadIdx.x;
    int wave = gid >> 6, lane = gid & 63;
    if (wave >= rows) return;
    const int PER = (L_ + 63) / 64;
    float v[PER];
    float m = -1e30f;
    int cnt = 0;
    for (int k = lane; k < L_; k += 64) {
        v[cnt] = P0[(long)wave * L_ + k];
        m = fmaxf(m, v[cnt]); cnt++;
    }
    #pragma unroll
    for (int off = 32; off; off >>= 1) m = fmaxf(m, __shfl_xor(m, off));
    float s = 0.f;
    for (int i = 0; i < cnt; i++) { v[i] = expf(v[i] - m); s += v[i]; }
    #pragma unroll
    for (int off = 32; off; off >>= 1) s += __shfl_xor(s, off);
    float inv = 1.f / s;
    cnt = 0;
    for (int k = lane; k < L_; k += 64) {
        float val = v[cnt++] * inv;
        X[(long)wave * L_ + k] = val;
        Xb[(long)wave * LP_ + k] = bf_hi(val);
    }
    if (lane < LP_ - L_) Xb[(long)wave * LP_ + L_ + lane] = 0;
}

// ---------------------------------------------------------------------------
// K4: h1 GEMM with fused h0 epilogue (atomic into bf2-initialized Ht0)
// ---------------------------------------------------------------------------
__global__ __launch_bounds__(256) void h0gemm(
    const short* __restrict__ attnH, const short* __restrict__ F1T,
    const float* __restrict__ bf1, const float* __restrict__ Wf2,
    float* __restrict__ Ht0)
{
    __shared__ __align__(16) char sm[SMEM_MM_NS];
    int b = blockIdx.x;
    int l = (b & 7) * 128 + (b >> 3);             // XCD-chunked, G=1024
    int zb = l >> 6, by = (l >> 3) & 7, bx = l & 7;
    const short* Ap = attnH + (long)zb * N_ * LP_;
    const short* Bp = F1T + (long)zb * HD_ * LP_;
    mm_core<OUT_H0, false>(sm, bx, by, zb, Ap, nullptr, Bp, nullptr,
                           bf1, Ht0, nullptr, nullptr, Wf2,
                           N_, HD_, LP_, 0, LP_);
}

// ---------------------------------------------------------------------------
// Recurrence step v4: 320 threads = (g: 4 m-quarters) x (c: 80 cols). Each
// thread streams its 250-row Hin quarter ONCE carrying 4 accumulators (one
// per output row nl), prop read as wave-uniform float2 (L1 broadcast, 16 KB).
// Kills v2's 4x redundant Hin L2 traffic (1.28 MB -> 320 KB/block; steps
// were L2-BW-bound: 320 MB/step at ~34.5 TB/s ~ 9.3 us). No barriers or
// ds_reads in the inner loop (round-8 v3's poison); one LDS partial-reduce
// at the end. GRU tail unchanged.
// ---------------------------------------------------------------------------
__global__ __launch_bounds__(320) void step_kernel(
    const float* __restrict__ prop, const float* __restrict__ Hin,
    float* __restrict__ Hout,
    const float* __restrict__ W_ih, const float* __restrict__ b_ih,
    const float* __restrict__ W_hh, const float* __restrict__ b_hh)
{
    __shared__ float part[4][4][80];   // [g][nl][c] = 5120 B
    __shared__ float msg[4][80];
    int t = threadIdx.x;
    int g = t / 80, c = t - g * 80;    // g = m-quarter, c = col
    int n0 = blockIdx.x * 4;
    int m0 = g * 250;
    const float* hc = Hin + (long)m0 * 80 + c;
    const float* pr = prop + (long)n0 * N_ + m0;
    float a0 = 0.f, a1 = 0.f, a2 = 0.f, a3 = 0.f;
    #pragma unroll 2
    for (int m2 = 0; m2 < 250; m2 += 2) {
        float h0 = hc[(long)(m2 + 0) * 80];
        float h1 = hc[(long)(m2 + 1) * 80];
        float2 p0 = *(const float2*)(pr + 0 * N_ + m2);
        float2 p1 = *(const float2*)(pr + 1 * N_ + m2);
        float2 p2 = *(const float2*)(pr + 2 * N_ + m2);
        float2 p3 = *(const float2*)(pr + 3 * N_ + m2);
        a0 = fmaf(p0.x, h0, a0); a0 = fmaf(p0.y, h1, a0);
        a1 = fmaf(p1.x, h0, a1); a1 = fmaf(p1.y, h1, a1);
        a2 = fmaf(p2.x, h0, a2); a2 = fmaf(p2.y, h1, a2);
        a3 = fmaf(p3.x, h0, a3); a3 = fmaf(p3.y, h1, a3);
    }
    part[g][0][c] = a0;
    part[g][1][c] = a1;
    part[g][2][c] = a2;
    part[g][3][c] = a3;
    __syncthreads();
    // reduce over g; thread (g,c) now plays role (nl=g, c)
    msg[g][c] = tanhf((part[0][g][c] + part[1][g][c]) +
                      (part[2][g][c] + part[3][g][c]));
    __syncthreads();
    if (t < 64) {
        int nl2 = t >> 4, b = t & 15;
        int n2 = n0 + nl2;
        float xv[DD_], h[DD_];
        #pragma unroll
        for (int j = 0; j < DD_; j++) {
            xv[j] = msg[nl2][b * DD_ + j];
            h[j] = Hin[(long)n2 * 80 + b * DD_ + j];
        }
        float gi[3 * DD_], gh[3 * DD_];
        #pragma unroll
        for (int gg = 0; gg < 3 * DD_; gg++) {
            float a = b_ih[gg], cc = b_hh[gg];
            #pragma unroll
            for (int k = 0; k < DD_; k++) {
                a = fmaf(xv[k], W_ih[gg * DD_ + k], a);
                cc = fmaf(h[k], W_hh[gg * DD_ + k], cc);
            }
            gi[gg] = a; gh[gg] = cc;
        }
        #pragma unroll
        for (int j = 0; j < DD_; j++) {
            float rr = 1.f / (1.f + expf(-(gi[j] + gh[j])));
            float zz = 1.f / (1.f + expf(-(gi[DD_ + j] + gh[DD_ + j])));
            float nn2 = tanhf(gi[2 * DD_ + j] + rr * gh[2 * DD_ + j]);
            Hout[(long)n2 * 80 + b * DD_ + j] = (1.f - zz) * nn2 + zz * h[j];
        }
    }
}

// ---------------------------------------------------------------------------
// out_kernel v2: Wo1/bo1/Wo2 staged in LDS once per block (separate kernel,
// no occupancy coupling; L2 weight re-reads ~164 MB -> ~3.5 MB).
// ---------------------------------------------------------------------------
__global__ __launch_bounds__(256) void out_kernel(
    const float* __restrict__ ht, const float* __restrict__ Wo1,
    const float* __restrict__ bo1, const float* __restrict__ Wo2,
    const float* __restrict__ bo2, float* __restrict__ logits, int rows)
{
    __shared__ float w1[DD_][HD_];   // 10240 B
    __shared__ float w2[HD_];
    __shared__ float b1[HD_];
    int t = threadIdx.x;
    for (int j = t; j < HD_; j += 256) {
        w2[j] = Wo2[j];
        b1[j] = bo1[j];
        #pragma unroll
        for (int d = 0; d < DD_; d++) w1[d][j] = Wo1[d * HD_ + j];
    }
    __syncthreads();
    int wv = t >> 6, lane = t & 63;
    float bo2v = bo2[0];
    #pragma unroll
    for (int rr = 0; rr < 16; rr++) {
        int row = blockIdx.x * 64 + wv * 16 + rr;
        if (row >= rows) break;
        int b = row / N_, n = row - b * N_;
        float x[DD_];
        #pragma unroll
        for (int i = 0; i < DD_; i++) x[i] = ht[(long)n * (B_ * DD_) + b * DD_ + i];
        float acc = 0.f;
        for (int j = lane; j < HD_; j += 64) {
            float h = b1[j];
            #pragma unroll
            for (int d = 0; d < DD_; d++) h = fmaf(x[d], w1[d][j], h);
            h = fmaxf(h, 0.f);
            acc = fmaf(h, w2[j], acc);
        }
        #pragma unroll
        for (int off = 32; off; off >>= 1) acc += __shfl_down(acc, off);
        if (lane == 0) logits[row] = acc + bo2v;
    }
}

// ---------------------------------------------------------------------------
extern "C" void kernel_launch(void* const* d_in, const int* in_sizes, int n_in,
                              void* d_out, int out_size, void* d_ws, size_t ws_size,
                              hipStream_t stream)
{
    const float* feats   = (const float*)d_in[0];
    const float* embed   = (const float*)d_in[1];
    const int*   edges   = (const int*)  d_in[2];
    const float* W_key   = (const float*)d_in[3];
    const float* b_key   = (const float*)d_in[4];
    const float* W_query = (const float*)d_in[5];
    const float* b_query = (const float*)d_in[6];
    const float* Wf1     = (const float*)d_in[7];
    const float* bf1     = (const float*)d_in[8];
    const float* Wf2     = (const float*)d_in[9];
    const float* bf2     = (const float*)d_in[10];
    const float* Wr1     = (const float*)d_in[11];
    const float* br1     = (const float*)d_in[12];
    const float* Wr2     = (const float*)d_in[13];
    const float* br2     = (const float*)d_in[14];
    const float* Wo1     = (const float*)d_in[15];
    const float* bo1     = (const float*)d_in[16];
    const float* Wo2     = (const float*)d_in[17];
    const float* bo2     = (const float*)d_in[18];
    const float* W_ih    = (const float*)d_in[19];
    const float* b_ih    = (const float*)d_in[20];
    const float* W_hh    = (const float*)d_in[21];
    const float* b_hh    = (const float*)d_in[22];
    const float* W_clf   = (const float*)d_in[23];
    const float* b_clf   = (const float*)d_in[24];

    float* out_logits = (float*)d_out;
    float* out_attn   = out_logits + B_ * N_;
    float* out_img    = out_attn + (long)B_ * N_ * L_;

    char* p = (char*)d_ws;
    auto alloc = [&](size_t bytes) { void* r = (void*)p; p += (bytes + 255) & ~(size_t)255; return r; };
    float* pooled  = (float*)alloc((size_t)B_ * FD_ * 4);
    short* featsH  = (short*)alloc((size_t)B_ * L_ * FD_ * 2);
    short* featsL  = (short*)alloc((size_t)B_ * L_ * FD_ * 2);
    short* WkfH    = (short*)alloc((size_t)1024 * FD_ * 2);
    short* WkfL    = (short*)alloc((size_t)512 * FD_ * 2);
    short* WqTh    = (short*)alloc((size_t)HD_ * WDP_ * 2);
    short* WqTl    = (short*)alloc((size_t)HD_ * WDP_ * 2);
    short* Wr1T    = (short*)alloc((size_t)256 * EKP_ * 2);
    short* embH    = (short*)alloc((size_t)N_ * WDP_ * 2);
    short* embL    = (short*)alloc((size_t)N_ * WDP_ * 2);
    short* keysH   = (short*)alloc((size_t)B_ * L_ * HD_ * 2);
    short* keysL   = (short*)alloc((size_t)B_ * L_ * HD_ * 2);
    short* qH      = (short*)alloc((size_t)N_ * HD_ * 2);
    short* qL      = (short*)alloc((size_t)N_ * HD_ * 2);
    short* attnH   = (short*)alloc((size_t)B_ * N_ * LP_ * 2);
    short* F1T     = (short*)alloc((size_t)B_ * HD_ * LP_ * 2);
    float* prop    = (float*)alloc((size_t)N_ * N_ * 4);
    float* Ht0     = (float*)alloc((size_t)N_ * B_ * DD_ * 4);
    float* Ht1     = (float*)alloc((size_t)N_ * B_ * DD_ * 4);
    float* Pimg    = (float*)alloc((size_t)8 * B_ * NIMG_ * 4);
    float* Pattn   = (float*)alloc((size_t)B_ * N_ * L_ * 4);

    // K0: all prep (7363 blocks)
    prep<<<7363, 256, 0, stream>>>(prop, Ht0, bf2, feats, pooled, featsH, featsL,
                                   embed, embH, embL, W_key, Wf1, WkfH, WkfL,
                                   W_query, WqTh, WqTl, Wr1, Wr1T, F1T);

    // K1: fused keys + F1 + queries + edge + clf (1750 blocks, round-7 clf)
    mega1<<<1750, 256, 0, stream>>>(featsH, featsL, WkfH, WkfL, b_key, keysH, keysL, F1T,
                                    embH, embL, WqTh, WqTl, b_query, qH, qL,
                                    edges, Wr1T, br1, Wr2, br2, prop,
                                    pooled, W_clf, b_clf, Pimg);

    // K2: scores (single K=512 plane, 512 blocks) + softmax_img
    mega2<<<516, 256, 0, stream>>>(qH, qL, keysH, keysL, Pattn, Pimg, out_img);

    // K3: softmax over 196 (single plane), writes out_attn + attnH (stride 224)
    softmax_attn<<<(B_ * N_ * 64 + 255) / 256, 256, 0, stream>>>(
        Pattn, out_attn, attnH, B_ * N_);

    // K4: h1 GEMM with fused h0 epilogue
    h0gemm<<<1024, 256, 0, stream>>>(attnH, F1T, bf1, Wf2, Ht0);

    // K5..K10: recurrence + output head
    {
        float* hin = Ht0;
        float* hout = Ht1;
        for (int step = 0; step < TMAX_; step++) {
            step_kernel<<<N_ / 4, 320, 0, stream>>>(prop, hin, hout,
                                                    W_ih, b_ih, W_hh, b_hh);
            float* tmp = hin; hin = hout; hout = tmp;
        }
        out_kernel<<<250, 256, 0, stream>>>(hin, Wo1, bo1, Wo2, bo2,
                                            out_logits, B_ * N_);
    }
}

// Round 14
// 439.136 us; speedup vs baseline: 1.2265x; 1.2265x over previous
//
#include <hip/hip_runtime.h>
#include <hip/hip_bf16.h>
#include <math.h>

// Problem constants
#define B_   16
#define L_   196
#define FD_  2048
#define N_   1000
#define WD_  300
#define HD_  512
#define DD_  5
#define E_   50000
#define TMAX_ 5
#define NIMG_ 1000
#define WDP_ 320   // WD_ padded to multiple of 32 (zero-filled)
#define LP_  224   // L_ padded to multiple of 32 (zero-filled)
#define EKP_ 640   // edge-MLP K: [embH_pad(320) | embH_pad(320)]

typedef __attribute__((ext_vector_type(8))) short bf16x8;
typedef __attribute__((ext_vector_type(4))) float f32x4;

// Double-buffered gl16 staging:
// mm split: 2 x (AsH 8192 + AsL 8192 + BsH 4096 + BsL 4096) = 49152
// mm ns   : 2 x (8192 + 4096) = 24576
// edge    : 2 x (As 4096 + Bs 16384) = 40960, extras at 40960..42752
#define SMEM_MEGA1    49152
#define SMEM_MM_SPLIT 49152
#define SMEM_MM_NS    24576
#define SMEM_PREP     4352

// raw barrier / counted waits (memory clobber pins memory-op ordering)
#define SBAR()    asm volatile("s_barrier" ::: "memory")
#define WVM(N)    asm volatile("s_waitcnt vmcnt(" #N ")" ::: "memory")

__device__ __forceinline__ short bf_hi(float x) {
    unsigned u = __float_as_uint(x);
    unsigned r = u + 0x7fffu + ((u >> 16) & 1u);
    return (short)(r >> 16);
}
__device__ __forceinline__ float bf2f_(short s) {
    return __uint_as_float(((unsigned)(unsigned short)s) << 16);
}

// direct global->LDS 16B copy (dest = wave-uniform base + lane*16)
__device__ __forceinline__ void gl16(const short* g, char* l) {
    __builtin_amdgcn_global_load_lds(
        (const __attribute__((address_space(1))) void*)g,
        (__attribute__((address_space(3))) void*)l, 16, 0, 0);
}

// ---------------------------------------------------------------------------
// MFMA GEMM core v5 (validated rounds 6/7/9/12): gl16 into double-buffered
// unpadded [row][32] LDS, both-sides XOR-chunk swizzle (BANK_CONFLICT=0),
// 2-deep pipeline with counted vmcnt (tile k+1 in flight across barriers).
// ---------------------------------------------------------------------------
#define OUT_SPLIT 1
#define OUT_SC    2
#define OUT_F1T   3
#define OUT_H0    4

template<int OUTMODE, bool SPLIT>
__device__ __forceinline__ void mm_core(
    char* sm, int bx, int by, int zb,
    const short* __restrict__ Ah, const short* __restrict__ Al,
    const short* __restrict__ Bh, const short* __restrict__ Bl,
    const float* __restrict__ bias, void* __restrict__ C0, void* __restrict__ C1,
    void* __restrict__ C2, const float* __restrict__ W2,
    int M, int N, int K, int kbeg, int kend)
{
    const int PBUF = SPLIT ? 24576 : 12288;
    char* AsH = sm;                               // [128][32] shorts = 8192 B
    char* AsL = sm + 8192;                        // SPLIT only
    char* BsH = sm + (SPLIT ? 16384 : 8192);      // [64][32] shorts = 4096 B
    char* BsL = sm + 20480;                       // SPLIT only
    int t = threadIdx.x;
    int lane = t & 63, w = t >> 6;
    int q = lane >> 4, r = lane & 15;
    int row0 = by * 128, col0 = bx * 64;

    int srow = t >> 2, cd = t & 3;
    int cg = cd ^ ((srow >> 1) & 3);              // pre-swizzled source chunk
    int gA0 = row0 + srow;       if (gA0 >= M) gA0 = M - 1;
    int gA1 = row0 + 64 + srow;  if (gA1 >= M) gA1 = M - 1;
    int gB  = col0 + srow;       if (gB  >= N) gB  = N - 1;
    const short* pA0 = Ah + (long)gA0 * K + cg * 8 + kbeg;
    const short* pA1 = Ah + (long)gA1 * K + cg * 8 + kbeg;
    const short* pB  = Bh + (long)gB  * K + cg * 8 + kbeg;
    const short* pA0l = Ah; const short* pA1l = Ah; const short* pBl = Bh;
    if (SPLIT) {
        pA0l = Al + (long)gA0 * K + cg * 8 + kbeg;
        pA1l = Al + (long)gA1 * K + cg * 8 + kbeg;
        pBl  = Bl + (long)gB  * K + cg * 8 + kbeg;
    }
    char* dA0 = AsH + t * 16;
    char* dA1 = AsH + 4096 + t * 16;
    char* dB  = BsH + t * 16;
    char* dA0l = AsL + t * 16;
    char* dA1l = AsL + 4096 + t * 16;
    char* dBl  = BsL + t * 16;

    int x = (q ^ ((r >> 1) & 3)) * 16;
    int aoff0 = (w * 32 + r) * 64 + x;
    int aoff1 = aoff0 + 1024;                     // +16 rows
    int boff[4];
    #pragma unroll
    for (int ct = 0; ct < 4; ct++) boff[ct] = (ct * 16 + r) * 64 + x;

    f32x4 zero4 = {0.f, 0.f, 0.f, 0.f};
    f32x4 acc[2][4];
    #pragma unroll
    for (int i = 0; i < 2; i++)
        #pragma unroll
        for (int j = 0; j < 4; j++) acc[i][j] = zero4;

    auto stage = [&](int ks) {
        int off = (ks & 1) * PBUF;
        int ko = ks * 32;
        gl16(pA0 + ko, dA0 + off);
        gl16(pA1 + ko, dA1 + off);
        gl16(pB  + ko, dB  + off);
        if (SPLIT) {
            gl16(pA0l + ko, dA0l + off);
            gl16(pA1l + ko, dA1l + off);
            gl16(pBl  + ko, dBl  + off);
        }
    };

    int nk = (kend - kbeg) >> 5;
    stage(0);
    for (int ks = 0; ks < nk; ks++) {
        if (ks + 1 < nk) {
            stage(ks + 1);                 // into buf^1 (safe: prev trailing bar)
            if (SPLIT) { WVM(6); } else { WVM(3); }   // wait tile ks only
        } else {
            WVM(0);
        }
        SBAR();                            // tile ks visible to all waves

        int cur = (ks & 1) * PBUF;
        bf16x8 ah0 = *(const bf16x8*)(AsH + cur + aoff0);
        bf16x8 ah1 = *(const bf16x8*)(AsH + cur + aoff1);
        bf16x8 al0, al1;
        if (SPLIT) {
            al0 = *(const bf16x8*)(AsL + cur + aoff0);
            al1 = *(const bf16x8*)(AsL + cur + aoff1);
        }
        #pragma unroll
        for (int ct = 0; ct < 4; ct++) {
            bf16x8 bh = *(const bf16x8*)(BsH + cur + boff[ct]);
            acc[0][ct] = __builtin_amdgcn_mfma_f32_16x16x32_bf16(ah0, bh, acc[0][ct], 0, 0, 0);
            acc[1][ct] = __builtin_amdgcn_mfma_f32_16x16x32_bf16(ah1, bh, acc[1][ct], 0, 0, 0);
            if (SPLIT) {
                acc[0][ct] = __builtin_amdgcn_mfma_f32_16x16x32_bf16(al0, bh, acc[0][ct], 0, 0, 0);
                acc[1][ct] = __builtin_amdgcn_mfma_f32_16x16x32_bf16(al1, bh, acc[1][ct], 0, 0, 0);
                bf16x8 bl = *(const bf16x8*)(BsL + cur + boff[ct]);
                acc[0][ct] = __builtin_amdgcn_mfma_f32_16x16x32_bf16(ah0, bl, acc[0][ct], 0, 0, 0);
                acc[1][ct] = __builtin_amdgcn_mfma_f32_16x16x32_bf16(ah1, bl, acc[1][ct], 0, 0, 0);
            }
        }
        if (ks + 1 < nk) SBAR();           // reads done before buf restage (ks+2)
    }

    if (OUTMODE == OUT_H0) {
        float s[2][4][DD_];
        #pragma unroll
        for (int i = 0; i < 2; i++)
            #pragma unroll
            for (int reg = 0; reg < 4; reg++)
                #pragma unroll
                for (int d = 0; d < DD_; d++) s[i][reg][d] = 0.f;
        #pragma unroll
        for (int i = 0; i < 2; i++) {
            #pragma unroll
            for (int ct = 0; ct < 4; ct++) {
                int n = col0 + ct * 16 + r;
                float w2v[DD_];
                #pragma unroll
                for (int d = 0; d < DD_; d++) w2v[d] = W2[n * DD_ + d];
                float b1 = bias[n];
                #pragma unroll
                for (int reg = 0; reg < 4; reg++) {
                    int m = row0 + w * 32 + i * 16 + q * 4 + reg;
                    if (m >= M) continue;
                    float val = fmaxf(acc[i][ct][reg] + b1, 0.f);
                    #pragma unroll
                    for (int d = 0; d < DD_; d++) s[i][reg][d] = fmaf(val, w2v[d], s[i][reg][d]);
                }
            }
        }
        #pragma unroll
        for (int i = 0; i < 2; i++)
            #pragma unroll
            for (int reg = 0; reg < 4; reg++)
                #pragma unroll
                for (int d = 0; d < DD_; d++) {
                    float v = s[i][reg][d];
                    v += __shfl_xor(v, 1);
                    v += __shfl_xor(v, 2);
                    v += __shfl_xor(v, 4);
                    v += __shfl_xor(v, 8);
                    if (r == 0) {
                        int m = row0 + w * 32 + i * 16 + q * 4 + reg;
                        if (m < M)
                            atomicAdd(&((float*)C0)[(long)m * (B_ * DD_) + zb * DD_ + d], v);
                    }
                }
        return;
    }

    #pragma unroll
    for (int i = 0; i < 2; i++) {
        #pragma unroll
        for (int ct = 0; ct < 4; ct++) {
            #pragma unroll
            for (int reg = 0; reg < 4; reg++) {
                int m = row0 + w * 32 + i * 16 + q * 4 + reg;
                int n = col0 + ct * 16 + r;
                if (m >= M || n >= N) continue;
                float v = acc[i][ct][reg];
                if (OUTMODE == OUT_SC) {
                    ((float*)C0)[(long)m * N + n] = v;
                } else if (OUTMODE == OUT_F1T) {
                    int b = m / 196, l = m - b * 196;
                    ((short*)C2)[((long)b * 512 + n) * LP_ + l] = bf_hi(v);
                } else { // OUT_SPLIT
                    float v2 = v + bias[n];
                    long idx = (long)m * N + n;
                    short hi = bf_hi(v2);
                    ((short*)C0)[idx] = hi;
                    ((short*)C1)[idx] = bf_hi(v2 - bf2f_(hi));
                }
            }
        }
    }
}

// ---------------------------------------------------------------------------
// Edge MLP core v3 (validated round 6)
// ---------------------------------------------------------------------------
__device__ __forceinline__ void edge_core(
    char* sm, int be,
    const short* __restrict__ embedH, const int* __restrict__ edges,
    const short* __restrict__ Wr1T, const float* __restrict__ br1,
    const float* __restrict__ Wr2, const float* __restrict__ br2,
    float* __restrict__ prop)
{
    const int EPBUF = 20480;
    char* As = sm;                 // [64][32] shorts  = 4096 B
    char* Bs = sm + 4096;          // [256][32] shorts = 16384 B
    int* src = (int*)(sm + 40960);
    int* dst = (int*)(sm + 41216);
    float (*part)[5] = (float(*)[5])(sm + 41472);
    int t = threadIdx.x;
    int e0 = be * 64;
    if (t < 64) {
        int e = e0 + t;
        src[t] = (e < E_) ? edges[e] : 0;
        dst[t] = (e < E_) ? edges[E_ + e] : 0;
    }
    __syncthreads();
    int lane = t & 63, w = t >> 6, q = lane >> 4, r = lane & 15;
    f32x4 zero4 = {0.f, 0.f, 0.f, 0.f};
    f32x4 acc[4][4];
    #pragma unroll
    for (int i = 0; i < 4; i++)
        #pragma unroll
        for (int j = 0; j < 4; j++) acc[i][j] = zero4;

    int srow = t >> 2, cd = t & 3;
    int cg = cd ^ ((srow >> 1) & 3);              // pre-swizzled source chunk
    const short* baseS = embedH + (long)src[srow] * WDP_ + cg * 8;
    const short* baseD = embedH + (long)dst[srow] * WDP_ + cg * 8;
    const short* pB = Wr1T + (long)srow * EKP_ + cg * 8;   // + i*64*EKP_
    char* dA = As + t * 16;
    char* dB = Bs + t * 16;                        // + i*4096

    int x = (q ^ ((r >> 1) & 3)) * 16;
    int aoff[4], boff[4];
    #pragma unroll
    for (int i = 0; i < 4; i++) {
        aoff[i] = (i * 16 + r) * 64 + x;
        boff[i] = (w * 64 + i * 16 + r) * 64 + x;
    }

    auto estage = [&](int ks) {
        int off = (ks & 1) * EPBUF;
        const short* pa = (ks < 10) ? baseS + ks * 32 : baseD + (ks - 10) * 32;
        gl16(pa, dA + off);
        #pragma unroll
        for (int i = 0; i < 4; i++)
            gl16(pB + (long)i * 64 * EKP_ + ks * 32, dB + i * 4096 + off);
    };

    estage(0);
    for (int ks = 0; ks < 20; ks++) {
        if (ks + 1 < 20) {
            estage(ks + 1);
            WVM(5);
        } else {
            WVM(0);
        }
        SBAR();

        int cur = (ks & 1) * EPBUF;
        bf16x8 af[4], bfr[4];
        #pragma unroll
        for (int rt = 0; rt < 4; rt++) af[rt] = *(const bf16x8*)(As + cur + aoff[rt]);
        #pragma unroll
        for (int ct = 0; ct < 4; ct++) bfr[ct] = *(const bf16x8*)(Bs + cur + boff[ct]);
        #pragma unroll
        for (int rt = 0; rt < 4; rt++)
            #pragma unroll
            for (int ct = 0; ct < 4; ct++)
                acc[rt][ct] = __builtin_amdgcn_mfma_f32_16x16x32_bf16(af[rt], bfr[ct], acc[rt][ct], 0, 0, 0);
        if (ks + 1 < 20) SBAR();
    }
    float b1v[4], w2v[4];
    #pragma unroll
    for (int ct = 0; ct < 4; ct++) {
        int u = w * 64 + ct * 16 + r;
        b1v[ct] = br1[u];
        w2v[ct] = Wr2[u];
    }
    #pragma unroll
    for (int rt = 0; rt < 4; rt++) {
        #pragma unroll
        for (int reg = 0; reg < 4; reg++) {
            float s = 0.f;
            #pragma unroll
            for (int ct = 0; ct < 4; ct++)
                s = fmaf(fmaxf(acc[rt][ct][reg] + b1v[ct], 0.f), w2v[ct], s);
            s += __shfl_xor(s, 1);
            s += __shfl_xor(s, 2);
            s += __shfl_xor(s, 4);
            s += __shfl_xor(s, 8);
            if (r == 0) part[rt * 16 + q * 4 + reg][w] = s;
        }
    }
    __syncthreads();
    if (t < 64 && e0 + t < E_) {
        float s = part[t][0] + part[t][1] + part[t][2] + part[t][3];
        atomicAdd(&prop[(long)src[t] * N_ + dst[t]], tanhf(s + br2[0]));
    }
}

// ---------------------------------------------------------------------------
// transpose+convert core. Kd = data K (loads), Ks = storage stride/write bound
// ---------------------------------------------------------------------------
__device__ __forceinline__ void transconv_core(
    char* sm, int bx, int by,
    const float* __restrict__ in, short* __restrict__ outH, short* __restrict__ outL,
    int Kd, int N, int Ks)
{
    float (*tile)[33] = (float(*)[33])sm;
    int k0 = bx * 32, n0 = by * 32;
    int t = threadIdx.x;
    int tr = t >> 5, tc = t & 31;
    #pragma unroll
    for (int i = 0; i < 4; i++) {
        int k = k0 + tr + i * 8, n = n0 + tc;
        tile[tr + i * 8][tc] = (k < Kd && n < N) ? in[(long)k * N + n] : 0.f;
    }
    __syncthreads();
    #pragma unroll
    for (int i = 0; i < 4; i++) {
        int n = n0 + tr + i * 8, k = k0 + tc;
        if (n < N && k < Ks) {
            float x = tile[tc][tr + i * 8];
            short hi = bf_hi(x);
            outH[(long)n * Ks + k] = hi;
            if (outL) outL[(long)n * Ks + k] = bf_hi(x - bf2f_(hi));
        }
    }
}

// ---------------------------------------------------------------------------
// K0: all prep (round-7 configuration, 7459 blocks)
// ---------------------------------------------------------------------------
__global__ __launch_bounds__(256) void prep(
    float* __restrict__ prop, float* __restrict__ Ht0, const float* __restrict__ bf2,
    const float* __restrict__ feats, float* __restrict__ pooled,
    short* __restrict__ featsH, short* __restrict__ featsL,
    const float* __restrict__ embed, short* __restrict__ embH, short* __restrict__ embL,
    const float* __restrict__ W_key, const float* __restrict__ Wf1,
    short* __restrict__ WkfH, short* __restrict__ WkfL,
    const float* __restrict__ W_query, short* __restrict__ WqTh, short* __restrict__ WqTl,
    const float* __restrict__ Wr1, short* __restrict__ Wr1T, short* __restrict__ F1T)
{
    __shared__ __align__(16) char sm[SMEM_PREP];
    int b = blockIdx.x, t = threadIdx.x;
    if (b < 977) {
        int i = (b * 256 + t) * 4;
        if (i < N_ * N_) { float4 z = {0.f, 0.f, 0.f, 0.f}; *(float4*)(prop + i) = z; }
    } else if (b < 1290) {
        int i = (b - 977) * 256 + t;
        if (i < N_ * B_ * DD_) Ht0[i] = bf2[i % DD_];
    } else if (b < 1418) {
        int idx = (b - 1290) * 256 + t;
        int bb = idx / FD_, f = idx % FD_;
        const float* p = feats + (long)bb * L_ * FD_ + f;
        float acc = 0.f;
        for (int l = 0; l < L_; l++) acc += p[(long)l * FD_];
        pooled[idx] = acc * (1.0f / L_);
    } else if (b < 4554) {
        long i = ((long)(b - 1418) * 256 + t) * 8;
        float4 v0 = *(const float4*)(feats + i);
        float4 v1 = *(const float4*)(feats + i + 4);
        float xs[8] = {v0.x, v0.y, v0.z, v0.w, v1.x, v1.y, v1.z, v1.w};
        short h[8], l8[8];
        #pragma unroll
        for (int j = 0; j < 8; j++) {
            h[j] = bf_hi(xs[j]);
            l8[j] = bf_hi(xs[j] - bf2f_(h[j]));
        }
        *(int4*)(featsH + i) = *(int4*)h;
        *(int4*)(featsL + i) = *(int4*)l8;
    } else if (b < 4867) {
        // embed -> embH/embL, strided WDP_=320, zero pad cols 300..319
        int i = ((b - 4554) * 256 + t) * 4;
        if (i < N_ * WDP_) {
            int n = i / WDP_, c = i - n * WDP_;
            short h[4], l4[4];
            if (c < WD_) {     // WD_%4==0, no straddle
                float4 v = *(const float4*)(embed + (long)n * WD_ + c);
                float xs[4] = {v.x, v.y, v.z, v.w};
                #pragma unroll
                for (int j = 0; j < 4; j++) {
                    h[j] = bf_hi(xs[j]);
                    l4[j] = bf_hi(xs[j] - bf2f_(h[j]));
                }
            } else {
                #pragma unroll
                for (int j = 0; j < 4; j++) { h[j] = 0; l4[j] = 0; }
            }
            *(int2*)(embH + (long)n * WDP_ + c) = *(int2*)h;
            *(int2*)(embL + (long)n * WDP_ + c) = *(int2*)l4;
        }
    } else if (b < 5891) {
        int bb = b - 4867;
        transconv_core(sm, bb % 64, bb / 64, W_key, WkfH, WkfL, FD_, HD_, FD_);
    } else if (b < 6915) {
        int bb = b - 5891;
        transconv_core(sm, bb % 64, bb / 64, Wf1, WkfH + (size_t)512 * FD_, nullptr, FD_, HD_, FD_);
    } else if (b < 7075) {
        int bb = b - 6915;
        transconv_core(sm, bb % 10, bb / 10, W_query, WqTh, WqTl, WD_, HD_, WDP_);
    } else if (b < 7235) {
        // Wr1 [600][256] -> Wr1T640 [256][640]: out col k<320 <- row k (valid k<300),
        // k>=320 <- row k-20 (valid k<620); stripes zeroed.
        int bb = b - 7075;                 // 160 blocks: 20 k-tiles x 8 n-tiles
        int bx = bb % 20, by = bb / 20;
        float (*tile)[33] = (float(*)[33])sm;
        int k0 = bx * 32, n0 = by * 32;
        int tr = t >> 5, tc = t & 31;
        #pragma unroll
        for (int i = 0; i < 4; i++) {
            int kout = k0 + tr + i * 8, n = n0 + tc;
            int kin = (kout < 320) ? kout : kout - 20;
            bool valid = (kout < 320) ? (kout < 300) : (kout < 620);
            tile[tr + i * 8][tc] = valid ? Wr1[(long)kin * 256 + n] : 0.f;
        }
        __syncthreads();
        #pragma unroll
        for (int i = 0; i < 4; i++) {
            int n = n0 + tr + i * 8, k = k0 + tc;
            Wr1T[(long)n * EKP_ + k] = bf_hi(tile[tc][tr + i * 8]);
        }
    } else {
        // zero ONLY F1T pad cols 196..223 (7 int2 per row, 8192 rows = 224 blocks)
        int idx = (b - 7235) * 256 + t;    // 57344 = 8192 rows * 7
        int row = idx / 7, j = idx - row * 7;
        int2 z2; z2.x = 0; z2.y = 0;
        *(int2*)(F1T + (long)row * LP_ + 196 + j * 4) = z2;
    }
}

// ---------------------------------------------------------------------------
// K1: FUSED keys(split) + F1 + queries + edge + clf (1750 blocks)
// ---------------------------------------------------------------------------
__global__ __launch_bounds__(256) void mega1(
    const short* __restrict__ featsH, const short* __restrict__ featsL,
    const short* __restrict__ WkfH, const short* __restrict__ WkfL,
    const float* __restrict__ b_key, short* __restrict__ keysH, short* __restrict__ keysL,
    short* __restrict__ F1T,
    const short* __restrict__ embH, const short* __restrict__ embL,
    const short* __restrict__ WqTh, const short* __restrict__ WqTl,
    const float* __restrict__ b_query, short* __restrict__ qH, short* __restrict__ qL,
    const int* __restrict__ edges, const short* __restrict__ Wr1T,
    const float* __restrict__ br1, const float* __restrict__ Wr2,
    const float* __restrict__ br2, float* __restrict__ prop,
    const float* __restrict__ pooled, const float* __restrict__ W_clf,
    const float* __restrict__ b_clf, float* __restrict__ Pimg)
{
    __shared__ __align__(16) char sm[SMEM_MEGA1];
    int b = blockIdx.x;
    if (b < 200) {
        int l = (b & 7) * 25 + (b >> 3);          // XCD-chunked, G=200
        mm_core<OUT_SPLIT, true>(sm, l & 7, l >> 3, 0,
            featsH, featsL, WkfH, WkfL, b_key,
            keysH, keysL, nullptr, nullptr, B_ * L_, 512, FD_, 0, FD_);
    } else if (b < 400) {
        int bb = b - 200;
        int l = (bb & 7) * 25 + (bb >> 3);        // XCD-chunked, G=200
        mm_core<OUT_F1T, false>(sm, l & 7, l >> 3, 0,
            featsH, nullptr, WkfH + (size_t)512 * FD_, nullptr, nullptr,
            nullptr, nullptr, F1T, nullptr, B_ * L_, 512, FD_, 0, FD_);
    } else if (b < 464) {
        int bb = b - 400;
        int l = (bb & 7) * 8 + (bb >> 3);         // XCD-chunked, G=64
        mm_core<OUT_SPLIT, true>(sm, l & 7, l >> 3, 0,
            embH, embL, WqTh, WqTl, b_query,
            qH, qL, nullptr, nullptr, N_, HD_, WDP_, 0, WDP_);
    } else if (b < 1246) {
        edge_core(sm, b - 464, embH, edges, Wr1T, br1, Wr2, br2, prop);
    } else {
        int bb = b - 1246;
        int ks = bb / 63, ix = bb % 63;
        int i = ix * 256 + threadIdx.x;
        if (i < B_ * NIMG_) {
            int bi = i / NIMG_, n = i % NIMG_;
            const float* p = pooled + (long)bi * FD_ + ks * 256;
            const float* w = W_clf + (long)(ks * 256) * NIMG_ + n;
            float acc = (ks == 0) ? b_clf[n] : 0.f;
            #pragma unroll 4
            for (int k = 0; k < 256; k++) acc = fmaf(p[k], w[(long)k * NIMG_], acc);
            Pimg[(long)ks * (B_ * NIMG_) + i] = acc;
        }
    }
}

// ---------------------------------------------------------------------------
// K2: scores GEMM, single K=512 plane (512 blocks x 16 k-steps) + softmax_img
// ---------------------------------------------------------------------------
__global__ __launch_bounds__(256) void mega2(
    const short* __restrict__ qH, const short* __restrict__ qL,
    const short* __restrict__ keysH, const short* __restrict__ keysL,
    float* __restrict__ Pattn,
    const float* __restrict__ Pimg, float* __restrict__ out_img)
{
    __shared__ __align__(16) char sm[SMEM_MM_SPLIT];
    int b = blockIdx.x;
    if (b < 512) {
        int l = (b & 7) * 64 + (b >> 3);          // XCD-chunked, G=512
        int zb = l >> 5, by = (l >> 2) & 7, bx = l & 3;
        const short* Bh = keysH + (long)zb * L_ * HD_;
        const short* Bl = keysL + (long)zb * L_ * HD_;
        float* C0 = Pattn + (long)zb * N_ * L_;
        mm_core<OUT_SC, true>(sm, bx, by, 0, qH, qL, Bh, Bl, nullptr,
                              C0, nullptr, nullptr, nullptr,
                              N_, L_, HD_, 0, HD_);
    } else {
        int t = threadIdx.x;
        int wave = (b - 512) * 4 + (t >> 6), lane = t & 63;
        if (wave >= B_) return;
        const int PER = (NIMG_ + 63) / 64;
        float v[PER];
        float m = -1e30f;
        int cnt = 0;
        for (int k = lane; k < NIMG_; k += 64) {
            float s = 0.f;
            #pragma unroll
            for (int ks = 0; ks < 8; ks++) s += Pimg[(long)ks * (B_ * NIMG_) + wave * NIMG_ + k];
            v[cnt] = s; m = fmaxf(m, s); cnt++;
        }
        #pragma unroll
        for (int off = 32; off; off >>= 1) m = fmaxf(m, __shfl_xor(m, off));
        float s = 0.f;
        for (int i = 0; i < cnt; i++) { v[i] = expf(v[i] - m); s += v[i]; }
        #pragma unroll
        for (int off = 32; off; off >>= 1) s += __shfl_xor(s, off);
        float inv = 1.f / s;
        cnt = 0;
        for (int k = lane; k < NIMG_; k += 64) out_img[(long)wave * NIMG_ + k] = v[cnt++] * inv;
    }
}

// ---------------------------------------------------------------------------
// K3: softmax over 196 of single-plane P; writes out_attn fp32 + attnH bf16
// ---------------------------------------------------------------------------
__global__ void softmax_attn(const float* __restrict__ P0,
                             float* __restrict__ X, short* __restrict__ Xb, int rows)
{
    int gid = blockIdx.x * blockDim.x + threadIdx.x;
    int wave = gid >> 6, lane = gid & 63;
    if (wave >= rows) return;
    const int PER = (L_ + 63) / 64;
    float v[PER];
    float m = -1e30f;
    int cnt = 0;
    for (int k = lane; k < L_; k += 64) {
        v[cnt] = P0[(long)wave * L_ + k];
        m = fmaxf(m, v[cnt]); cnt++;
    }
    #pragma unroll
    for (int off = 32; off; off >>= 1) m = fmaxf(m, __shfl_xor(m, off));
    float s = 0.f;
    for (int i = 0; i < cnt; i++) { v[i] = expf(v[i] - m); s += v[i]; }
    #pragma unroll
    for (int off = 32; off; off >>= 1) s += __shfl_xor(s, off);
    float inv = 1.f / s;
    cnt = 0;
    for (int k = lane; k < L_; k += 64) {
        float val = v[cnt++] * inv;
        X[(long)wave * L_ + k] = val;
        Xb[(long)wave * LP_ + k] = bf_hi(val);
    }
    if (lane < LP_ - L_) Xb[(long)wave * LP_ + L_ + lane] = 0;
}

// ---------------------------------------------------------------------------
// K4: h1 GEMM with fused h0 epilogue (atomic into bf2-initialized Ht0)
// ---------------------------------------------------------------------------
__global__ __launch_bounds__(256) void h0gemm(
    const short* __restrict__ attnH, const short* __restrict__ F1T,
    const float* __restrict__ bf1, const float* __restrict__ Wf2,
    float* __restrict__ Ht0)
{
    __shared__ __align__(16) char sm[SMEM_MM_NS];
    int b = blockIdx.x;
    int l = (b & 7) * 128 + (b >> 3);             // XCD-chunked, G=1024
    int zb = l >> 6, by = (l >> 3) & 7, bx = l & 7;
    const short* Ap = attnH + (long)zb * N_ * LP_;
    const short* Bp = F1T + (long)zb * HD_ * LP_;
    mm_core<OUT_H0, false>(sm, bx, by, zb, Ap, nullptr, Bp, nullptr,
                           bf1, Ht0, nullptr, nullptr, Wf2,
                           N_, HD_, LP_, 0, LP_);
}

// ---------------------------------------------------------------------------
// Recurrence step v2 (round-7 measured best): 640 threads = 2 m-halves x
// 4 rows x 80 cols, 4 independent accumulators, LDS combine, GRU tail.
// (v3 round-8: LDS round-trips regressed; v4 round-13: halved TLP regressed.
// v2 at 10 waves/block is the practical floor for this latency-bound GEMV.)
// ---------------------------------------------------------------------------
__global__ __launch_bounds__(640) void step_kernel(
    const float* __restrict__ prop, const float* __restrict__ Hin,
    float* __restrict__ Hout,
    const float* __restrict__ W_ih, const float* __restrict__ b_ih,
    const float* __restrict__ W_hh, const float* __restrict__ b_hh)
{
    __shared__ float msg[2][4][80];
    int t = threadIdx.x;
    int half = t / 320, tt = t - half * 320;
    int nl = tt / 80, c = tt - nl * 80;
    int n = blockIdx.x * 4 + nl;
    const float* pr = prop + (long)n * N_ + half * 500;
    const float* hc = Hin + c + (long)half * 500 * 80;
    float a0 = 0.f, a1 = 0.f, a2 = 0.f, a3 = 0.f;
    #pragma unroll 4
    for (int m4 = 0; m4 < 500; m4 += 4) {
        float4 pv = *(const float4*)(pr + m4);
        a0 = fmaf(pv.x, hc[(long)(m4 + 0) * 80], a0);
        a1 = fmaf(pv.y, hc[(long)(m4 + 1) * 80], a1);
        a2 = fmaf(pv.z, hc[(long)(m4 + 2) * 80], a2);
        a3 = fmaf(pv.w, hc[(long)(m4 + 3) * 80], a3);
    }
    msg[half][nl][c] = (a0 + a1) + (a2 + a3);
    __syncthreads();
    if (t < 320) {
        int nl2 = t / 80, c2 = t - nl2 * 80;
        msg[0][nl2][c2] = tanhf(msg[0][nl2][c2] + msg[1][nl2][c2]);
    }
    __syncthreads();
    if (t < 64) {
        int nl2 = t >> 4, b = t & 15;
        int n2 = blockIdx.x * 4 + nl2;
        float xv[DD_], h[DD_];
        #pragma unroll
        for (int j = 0; j < DD_; j++) {
            xv[j] = msg[0][nl2][b * DD_ + j];
            h[j] = Hin[(long)n2 * 80 + b * DD_ + j];
        }
        float gi[3 * DD_], gh[3 * DD_];
        #pragma unroll
        for (int g = 0; g < 3 * DD_; g++) {
            float a = b_ih[g], cc = b_hh[g];
            #pragma unroll
            for (int k = 0; k < DD_; k++) {
                a = fmaf(xv[k], W_ih[g * DD_ + k], a);
                cc = fmaf(h[k], W_hh[g * DD_ + k], cc);
            }
            gi[g] = a; gh[g] = cc;
        }
        #pragma unroll
        for (int j = 0; j < DD_; j++) {
            float rr = 1.f / (1.f + expf(-(gi[j] + gh[j])));
            float zz = 1.f / (1.f + expf(-(gi[DD_ + j] + gh[DD_ + j])));
            float nn2 = tanhf(gi[2 * DD_ + j] + rr * gh[2 * DD_ + j]);
            Hout[(long)n2 * 80 + b * DD_ + j] = (1.f - zz) * nn2 + zz * h[j];
        }
    }
}

__global__ void out_kernel(const float* __restrict__ ht, const float* __restrict__ Wo1,
                           const float* __restrict__ bo1, const float* __restrict__ Wo2,
                           const float* __restrict__ bo2, float* __restrict__ logits, int rows)
{
    int gid = blockIdx.x * blockDim.x + threadIdx.x;
    int wave = gid >> 6, lane = gid & 63;
    if (wave >= rows) return;
    int b = wave / N_, n = wave % N_;
    float x[DD_];
    #pragma unroll
    for (int i = 0; i < DD_; i++) x[i] = ht[(long)n * (B_ * DD_) + b * DD_ + i];
    float acc = 0.f;
    for (int j = lane; j < HD_; j += 64) {
        float h = bo1[j];
        #pragma unroll
        for (int d = 0; d < DD_; d++) h = fmaf(x[d], Wo1[d * HD_ + j], h);
        h = fmaxf(h, 0.f);
        acc = fmaf(h, Wo2[j], acc);
    }
    #pragma unroll
    for (int off = 32; off; off >>= 1) acc += __shfl_down(acc, off);
    if (lane == 0) logits[wave] = acc + bo2[0];
}

// ---------------------------------------------------------------------------
extern "C" void kernel_launch(void* const* d_in, const int* in_sizes, int n_in,
                              void* d_out, int out_size, void* d_ws, size_t ws_size,
                              hipStream_t stream)
{
    const float* feats   = (const float*)d_in[0];
    const float* embed   = (const float*)d_in[1];
    const int*   edges   = (const int*)  d_in[2];
    const float* W_key   = (const float*)d_in[3];
    const float* b_key   = (const float*)d_in[4];
    const float* W_query = (const float*)d_in[5];
    const float* b_query = (const float*)d_in[6];
    const float* Wf1     = (const float*)d_in[7];
    const float* bf1     = (const float*)d_in[8];
    const float* Wf2     = (const float*)d_in[9];
    const float* bf2     = (const float*)d_in[10];
    const float* Wr1     = (const float*)d_in[11];
    const float* br1     = (const float*)d_in[12];
    const float* Wr2     = (const float*)d_in[13];
    const float* br2     = (const float*)d_in[14];
    const float* Wo1     = (const float*)d_in[15];
    const float* bo1     = (const float*)d_in[16];
    const float* Wo2     = (const float*)d_in[17];
    const float* bo2     = (const float*)d_in[18];
    const float* W_ih    = (const float*)d_in[19];
    const float* b_ih    = (const float*)d_in[20];
    const float* W_hh    = (const float*)d_in[21];
    const float* b_hh    = (const float*)d_in[22];
    const float* W_clf   = (const float*)d_in[23];
    const float* b_clf   = (const float*)d_in[24];

    float* out_logits = (float*)d_out;
    float* out_attn   = out_logits + B_ * N_;
    float* out_img    = out_attn + (long)B_ * N_ * L_;

    char* p = (char*)d_ws;
    auto alloc = [&](size_t bytes) { void* r = (void*)p; p += (bytes + 255) & ~(size_t)255; return r; };
    float* pooled  = (float*)alloc((size_t)B_ * FD_ * 4);
    short* featsH  = (short*)alloc((size_t)B_ * L_ * FD_ * 2);
    short* featsL  = (short*)alloc((size_t)B_ * L_ * FD_ * 2);
    short* WkfH    = (short*)alloc((size_t)1024 * FD_ * 2);
    short* WkfL    = (short*)alloc((size_t)512 * FD_ * 2);
    short* WqTh    = (short*)alloc((size_t)HD_ * WDP_ * 2);
    short* WqTl    = (short*)alloc((size_t)HD_ * WDP_ * 2);
    short* Wr1T    = (short*)alloc((size_t)256 * EKP_ * 2);
    short* embH    = (short*)alloc((size_t)N_ * WDP_ * 2);
    short* embL    = (short*)alloc((size_t)N_ * WDP_ * 2);
    short* keysH   = (short*)alloc((size_t)B_ * L_ * HD_ * 2);
    short* keysL   = (short*)alloc((size_t)B_ * L_ * HD_ * 2);
    short* qH      = (short*)alloc((size_t)N_ * HD_ * 2);
    short* qL      = (short*)alloc((size_t)N_ * HD_ * 2);
    short* attnH   = (short*)alloc((size_t)B_ * N_ * LP_ * 2);
    short* F1T     = (short*)alloc((size_t)B_ * HD_ * LP_ * 2);
    float* prop    = (float*)alloc((size_t)N_ * N_ * 4);
    float* Ht0     = (float*)alloc((size_t)N_ * B_ * DD_ * 4);
    float* Ht1     = (float*)alloc((size_t)N_ * B_ * DD_ * 4);
    float* Pimg    = (float*)alloc((size_t)8 * B_ * NIMG_ * 4);
    float* Pattn   = (float*)alloc((size_t)B_ * N_ * L_ * 4);

    // K0: all prep (7459 blocks; F1T branch zeroes pad cols only)
    prep<<<7459, 256, 0, stream>>>(prop, Ht0, bf2, feats, pooled, featsH, featsL,
                                   embed, embH, embL, W_key, Wf1, WkfH, WkfL,
                                   W_query, WqTh, WqTl, Wr1, Wr1T, F1T);

    // K1: fused keys + F1 + queries + edge + clf
    mega1<<<1750, 256, 0, stream>>>(featsH, featsL, WkfH, WkfL, b_key, keysH, keysL, F1T,
                                    embH, embL, WqTh, WqTl, b_query, qH, qL,
                                    edges, Wr1T, br1, Wr2, br2, prop,
                                    pooled, W_clf, b_clf, Pimg);

    // K2: scores (single K=512 plane, 512 blocks) + softmax_img
    mega2<<<516, 256, 0, stream>>>(qH, qL, keysH, keysL, Pattn, Pimg, out_img);

    // K3: softmax over 196 (single plane), writes out_attn + attnH (stride 224)
    softmax_attn<<<(B_ * N_ * 64 + 255) / 256, 256, 0, stream>>>(
        Pattn, out_attn, attnH, B_ * N_);

    // K4: h1 GEMM with fused h0 epilogue
    h0gemm<<<1024, 256, 0, stream>>>(attnH, F1T, bf1, Wf2, Ht0);

    // K5..K10: recurrence + output head
    {
        float* hin = Ht0;
        float* hout = Ht1;
        for (int step = 0; step < TMAX_; step++) {
            step_kernel<<<N_ / 4, 640, 0, stream>>>(prop, hin, hout,
                                                    W_ih, b_ih, W_hh, b_hh);
            float* tmp = hin; hin = hout; hout = tmp;
        }
        out_kernel<<<(B_ * N_ * 64 + 255) / 256, 256, 0, stream>>>(hin, Wo1, bo1, Wo2, bo2,
                                                                   out_logits, B_ * N_);
    }
}